// Round 2
// 148.732 us; speedup vs baseline: 1.0039x; 1.0039x over previous
//
#include <hip/hip_runtime.h>
#include <math.h>

// Problem constants
#define BSZ   2
#define NTOK  1024          // 32*32
#define CDIM  512
#define SENC  77
#define SKV   1101          // 77 + 1024 (order: self rows 0..1023, enc rows 1024..1100)
#define KROWS 1120          // padded KV rows (35 chunks of 32)
#define ENCD  768
#define NHEAD 64
#define DHEAD 8

typedef short short8 __attribute__((ext_vector_type(8)));
typedef float floatx4 __attribute__((ext_vector_type(4)));
typedef unsigned short ushortx4 __attribute__((ext_vector_type(4)));

__device__ __forceinline__ unsigned short f2bf(float f) {
    union { float f; unsigned int u; } v; v.f = f;
    unsigned int r = v.u + 0x7FFF + ((v.u >> 16) & 1);   // RNE
    return (unsigned short)(r >> 16);
}
__device__ __forceinline__ unsigned short rtzbf(float f) {
    return (unsigned short)(__float_as_uint(f) >> 16);   // RTZ (cancels in softmax norm)
}
// kv-column permutation so S-MFMA output regs ARE the PV A-frag
__device__ __forceinline__ int vslot(int kr) {
    return ((kr & 12) << 1) | ((kr & 16) >> 2) | (kr & 3);
}

// C-style casts: clang only allows addrspacecast via C-style
__device__ __forceinline__ void gld16(const void* g, void* l) {
    __builtin_amdgcn_global_load_lds(
        (const __attribute__((address_space(1))) unsigned int*)g,
        (__attribute__((address_space(3))) unsigned int*)l,
        16, 0, 0);
}

// ---------------------------------------------------------------- reductions
__device__ __forceinline__ float block_reduce_sum(float v) {
    #pragma unroll
    for (int off = 32; off > 0; off >>= 1) v += __shfl_down(v, off, 64);
    __shared__ float tmp[4];
    int lane = threadIdx.x & 63, wid = threadIdx.x >> 6;
    if (lane == 0) tmp[wid] = v;
    __syncthreads();
    if (wid == 0) {
        float r = (lane < 4) ? tmp[lane] : 0.f;
        r += __shfl_down(r, 2, 64);
        r += __shfl_down(r, 1, 64);
        if (lane == 0) tmp[0] = r;
    }
    __syncthreads();
    float out = tmp[0];
    __syncthreads();
    return out;
}

// ---------------------------------------------------------------- prep device parts
__device__ void layernorm_dev(int row, const float* __restrict__ x,
                              const float* __restrict__ sc, const float* __restrict__ bi,
                              unsigned short* __restrict__ out) {
    const float* xp = x + (size_t)row * ENCD;
    unsigned short* op = out + (size_t)row * ENCD;
    int t = threadIdx.x;
    float v0 = xp[t], v1 = xp[t + 256], v2 = xp[t + 512];
    float mu = block_reduce_sum(v0 + v1 + v2) * (1.f / ENCD);
    float d0 = v0 - mu, d1 = v1 - mu, d2 = v2 - mu;
    float var = block_reduce_sum(d0 * d0 + d1 * d1 + d2 * d2) * (1.f / ENCD);
    float rstd = rsqrtf(var + 1e-5f);
    op[t]       = f2bf(d0 * rstd * sc[t]       + bi[t]);
    op[t + 256] = f2bf(d1 * rstd * sc[t + 256] + bi[t + 256]);
    op[t + 512] = f2bf(d2 * rstd * sc[t + 512] + bi[t + 512]);
}

// single-pass register-resident GroupNorm
__device__ void groupnorm_dev(int bg, const float* __restrict__ x,
                              const float* __restrict__ sc, const float* __restrict__ bi,
                              unsigned short* __restrict__ out) {
    int b = bg >> 5, g = bg & 31;
    const float* xp = x + (size_t)b * NTOK * CDIM + g * 16;
    unsigned short* op = out + (size_t)b * NTOK * CDIM + g * 16;
    int t = threadIdx.x;
    int q = t & 3;

    float4 v[16];
    #pragma unroll
    for (int it = 0; it < 16; ++it) {
        int idx = t + it * 256;
        int n = idx >> 2;
        v[it] = *(const float4*)(xp + n * CDIM + q * 4);
    }
    float s = 0.f, ss = 0.f;
    #pragma unroll
    for (int it = 0; it < 16; ++it) {
        s  += (v[it].x + v[it].y) + (v[it].z + v[it].w);
        ss += (v[it].x * v[it].x + v[it].y * v[it].y)
            + (v[it].z * v[it].z + v[it].w * v[it].w);
    }
    float mu  = block_reduce_sum(s)  * (1.f / 16384.f);
    float msq = block_reduce_sum(ss) * (1.f / 16384.f);
    float rstd = rsqrtf(msq - mu * mu + 1e-5f);

    float4 s4 = *(const float4*)(sc + g * 16 + q * 4);
    float4 b4 = *(const float4*)(bi + g * 16 + q * 4);
    #pragma unroll
    for (int it = 0; it < 16; ++it) {
        int idx = t + it * 256;
        int n = idx >> 2;
        ushortx4 o;
        o[0] = f2bf((v[it].x - mu) * rstd * s4.x + b4.x);
        o[1] = f2bf((v[it].y - mu) * rstd * s4.y + b4.y);
        o[2] = f2bf((v[it].z - mu) * rstd * s4.z + b4.z);
        o[3] = f2bf((v[it].w - mu) * rstd * s4.w + b4.w);
        *(ushortx4*)(op + n * CDIM + q * 4) = o;
    }
}

// transpose+cast one 32x32 tile: W[K][N] fp32 -> Wt[N+roff][K] bf16
__device__ void tcast_dev(const float* __restrict__ W, unsigned short* __restrict__ Wt,
                          int K, int N, int roff, int local) {
    __shared__ float t[32][33];
    int bn = (local & 15) * 32, bk = (local >> 4) * 32;
    int lx = threadIdx.x & 31, ly = threadIdx.x >> 5;
    #pragma unroll
    for (int r = 0; r < 4; ++r)
        t[ly + 8 * r][lx] = W[(size_t)(bk + ly + 8 * r) * N + bn + lx];
    __syncthreads();
    #pragma unroll
    for (int r = 0; r < 4; ++r)
        Wt[(size_t)(roff + bn + ly + 8 * r) * K + bk + lx] = f2bf(t[lx][ly + 8 * r]);
}

// ---------------------------------------------------------------- fused preprocessing
__global__ __launch_bounds__(256) void prep_all(
        const float* __restrict__ Wq, const float* __restrict__ Wk, const float* __restrict__ Wv,
        const float* __restrict__ Wak, const float* __restrict__ Wav, const float* __restrict__ Wo,
        const float* __restrict__ bq, const float* __restrict__ bk, const float* __restrict__ bv,
        const float* __restrict__ bak, const float* __restrict__ bav,
        const float* __restrict__ enc, const float* __restrict__ ln_s, const float* __restrict__ ln_b,
        const float* __restrict__ x, const float* __restrict__ gn_s, const float* __restrict__ gn_b,
        unsigned short* __restrict__ Wqkv_t, unsigned short* __restrict__ Wakv_t,
        unsigned short* __restrict__ Wo_t,
        float* __restrict__ bqkv, float* __restrict__ bakv,
        unsigned short* __restrict__ enc_bf, unsigned short* __restrict__ hs_bf,
        unsigned short* __restrict__ Vh) {
    int bid = blockIdx.x;
    if (bid < 256)        tcast_dev(Wq,  Wqkv_t, 512, 512, 0,    bid);
    else if (bid < 512)   tcast_dev(Wk,  Wqkv_t, 512, 512, 512,  bid - 256);
    else if (bid < 768)   tcast_dev(Wv,  Wqkv_t, 512, 512, 1024, bid - 512);
    else if (bid < 1152)  tcast_dev(Wak, Wakv_t, 768, 512, 0,    bid - 768);
    else if (bid < 1536)  tcast_dev(Wav, Wakv_t, 768, 512, 512,  bid - 1152);
    else if (bid < 1792)  tcast_dev(Wo,  Wo_t,   512, 512, 0,    bid - 1536);
    else if (bid < 1802) {
        int i = (bid - 1792) * 256 + threadIdx.x;
        if (i < 512)        bqkv[i] = bq[i];
        else if (i < 1024)  bqkv[i] = bk[i - 512];
        else if (i < 1536)  bqkv[i] = bv[i - 1024];
        else if (i < 2048)  bakv[i - 1536] = bak[i - 1536];
        else if (i < 2560)  bakv[i - 1536] = bav[i - 2048];
    }
    else if (bid < 1956)  layernorm_dev(bid - 1802, enc, ln_s, ln_b, enc_bf);
    else if (bid < 2020)  groupnorm_dev(bid - 1956, x, gn_s, gn_b, hs_bf);
    else {
        // ones-row (ch=8) of Vh for the l=sum(p) trick (permutation-invariant)
        int i = (bid - 2020) * 256 + threadIdx.x;   // [0, 143360)
        int g = i / KROWS, kv = i - g * KROWS;      // g = b*64+h
        Vh[((size_t)g * 16 + 8) * KROWS + kv] = 0x3F80;  // bf16 1.0
    }
}

// ---------------------------------------------------------------- shared GEMM core
// 64x128 tile, 4 waves 2x2 (wave tile 32x64), 16x16x32 bf16 MFMA.
// T3-min 2-phase pipeline: double-buffered LDS, next K-step's global_load_lds
// issued BEFORE current step's ds_read+MFMA, ONE barrier per step (syncthreads
// drains vmcnt for the in-flight stage). Hides global latency at low occupancy.
// SWAP=false: acc[i][j] = C[row-in-regs][col-in-lanes]
// SWAP=true : acc[i][j] = C[col-in-regs][row-in-lanes]
template <bool SWAP>
__device__ __forceinline__ void gemm_core64(
        const unsigned short* __restrict__ A, int Mv,
        const unsigned short* __restrict__ Bt, int K,
        int m0, int n0, unsigned short* AsS, unsigned short* BsS,
        floatx4 (&acc)[2][4]) {
    int tid = threadIdx.x;
    int wv = tid >> 6, ln = tid & 63;
    int quad = ln >> 4, l16 = ln & 15;
    int wr = wv >> 1, wc = wv & 1;

    // per-thread staging addresses (constant across K-steps)
    int ar = tid >> 2, asg = tid & 3;
    int arow = m0 + ar; if (arow > Mv - 1) arow = Mv - 1;
    const unsigned short* Ap  = A  + (size_t)arow * K + asg * 8;
    int c0 = tid, c1 = 256 + tid;
    const unsigned short* Bp0 = Bt + (size_t)(n0 + (c0 >> 2)) * K + (c0 & 3) * 8;
    const unsigned short* Bp1 = Bt + (size_t)(n0 + (c1 >> 2)) * K + (c1 & 3) * 8;

    const int nt = K >> 5;
    int cur = 0;

    // prologue: stage tile 0
    gld16((const void*)Ap,  (void*)((char*)AsS + tid * 16));
    gld16((const void*)Bp0, (void*)((char*)BsS + c0 * 16));
    gld16((const void*)Bp1, (void*)((char*)BsS + c1 * 16));
    __syncthreads();   // compiler drains vmcnt(0) before barrier

    for (int t = 0; t < nt; ++t) {
        if (t + 1 < nt) {   // issue next-tile stage into the other buffer
            int k0 = (t + 1) * 32;
            int nb = cur ^ 1;
            gld16((const void*)(Ap  + k0), (void*)((char*)AsS + nb * 4096 + tid * 16));
            gld16((const void*)(Bp0 + k0), (void*)((char*)BsS + nb * 8192 + c0 * 16));
            gld16((const void*)(Bp1 + k0), (void*)((char*)BsS + nb * 8192 + c1 * 16));
        }
        short8 af[2], bf[4];
        #pragma unroll
        for (int i = 0; i < 2; ++i)
            af[i] = *(const short8*)(AsS + cur * 2048 + (wr * 32 + i * 16 + l16) * 32 + quad * 8);
        #pragma unroll
        for (int j = 0; j < 4; ++j)
            bf[j] = *(const short8*)(BsS + cur * 4096 + (wc * 64 + j * 16 + l16) * 32 + quad * 8);
        #pragma unroll
        for (int i = 0; i < 2; ++i)
            #pragma unroll
            for (int j = 0; j < 4; ++j)
                acc[i][j] = SWAP
                    ? __builtin_amdgcn_mfma_f32_16x16x32_bf16(bf[j], af[i], acc[i][j], 0, 0, 0)
                    : __builtin_amdgcn_mfma_f32_16x16x32_bf16(af[i], bf[j], acc[i][j], 0, 0, 0);
        if (t + 1 < nt) {
            __syncthreads();   // vmcnt(0)+lgkmcnt(0) drain: next buffer ready, cur reads done
            cur ^= 1;
        }
    }
}

// ---------------------------------------------------------------- merged projections
// blocks [0,384): QKV [2048,512]x[512,1536] -> head-major Qh/Kh/Vh (64-row tiles)
// blocks [384,408): enc KV [154,768]x[768,1024] -> Kh/Vh rows 1024+
__global__ __launch_bounds__(256) void proj_gemm(
        const unsigned short* __restrict__ hs_bf, const unsigned short* __restrict__ enc_bf,
        const unsigned short* __restrict__ Wqkv_t, const unsigned short* __restrict__ Wakv_t,
        const float* __restrict__ bqkv, const float* __restrict__ bakv,
        unsigned short* __restrict__ Qh, unsigned short* __restrict__ Kh,
        unsigned short* __restrict__ Vh) {
    __shared__ alignas(16) unsigned short AsS[2 * 64 * 32];
    __shared__ alignas(16) unsigned short BsS[2 * 128 * 32];
    floatx4 acc[2][4] = {};
    int bid = blockIdx.x;
    int tid = threadIdx.x;
    int wv = tid >> 6, ln = tid & 63;
    int quad = ln >> 4, l16 = ln & 15;
    int wr = wv >> 1, wc = wv & 1;
    const float ASCALE = 0.3535533905932738f * 1.4426950408889634f;  // 1/sqrt(8)*log2(e)

    if (bid < 384) {
        int n0 = (bid % 12) * 128, m0 = (bid / 12) * 64;
        gemm_core64<true>(hs_bf, 2048, Wqkv_t, 512, m0, n0, AsS, BsS, acc);
        #pragma unroll
        for (int i = 0; i < 2; ++i) {
            int tok = m0 + wr * 32 + i * 16 + l16;      // lane-varying token
            int b_ = tok >> 10, nn = tok & 1023;
            int vcol = (nn & ~31) | vslot(nn & 31);     // permuted V column
            #pragma unroll
            for (int j = 0; j < 4; ++j) {
                int colb = n0 + wc * 64 + j * 16 + quad * 4;   // wave-uniform
                float vv[4];
                #pragma unroll
                for (int r = 0; r < 4; ++r) vv[r] = acc[i][j][r] + bqkv[colb + r];
                if (colb < 512) {
                    int h = colb >> 3, c = colb & 7;
                    ushortx4 w = { f2bf(vv[0] * ASCALE), f2bf(vv[1] * ASCALE),
                                   f2bf(vv[2] * ASCALE), f2bf(vv[3] * ASCALE) };
                    *(ushortx4*)(Qh + ((size_t)(b_ * 64 + h) * 1024 + nn) * 8 + c) = w;
                } else if (colb < 1024) {
                    int cc = colb - 512, h = cc >> 3, c = cc & 7;
                    ushortx4 w = { f2bf(vv[0]), f2bf(vv[1]), f2bf(vv[2]), f2bf(vv[3]) };
                    *(ushortx4*)(Kh + ((size_t)(b_ * 64 + h) * KROWS + nn) * 8 + c) = w;
                } else {
                    int cc = colb - 1024, h = cc >> 3, c = cc & 7;
                    #pragma unroll
                    for (int r = 0; r < 4; ++r)
                        Vh[((size_t)(b_ * 64 + h) * 16 + c + r) * KROWS + vcol] = f2bf(vv[r]);
                }
            }
        }
    } else {
        int idx = bid - 384;
        int n0 = (idx % 8) * 128, m0 = (idx / 8) * 64;
        gemm_core64<true>(enc_bf, 154, Wakv_t, 768, m0, n0, AsS, BsS, acc);
        #pragma unroll
        for (int i = 0; i < 2; ++i) {
            int rg = m0 + wr * 32 + i * 16 + l16;       // lane-varying enc token
            bool ok = rg < 154;
            int b_ = rg >= 77;
            int jj = rg - 77 * b_;
            int e = 1024 + jj;
            int vcol = (e & ~31) | vslot(e & 31);       // permuted V column
            #pragma unroll
            for (int j = 0; j < 4; ++j) {
                int colb = n0 + wc * 64 + j * 16 + quad * 4;
                float vv[4];
                #pragma unroll
                for (int r = 0; r < 4; ++r) vv[r] = acc[i][j][r] + bakv[colb + r];
                if (colb < 512) {
                    int h = colb >> 3, c = colb & 7;
                    if (ok) {
                        ushortx4 w = { f2bf(vv[0]), f2bf(vv[1]), f2bf(vv[2]), f2bf(vv[3]) };
                        *(ushortx4*)(Kh + ((size_t)(b_ * 64 + h) * KROWS + 1024 + jj) * 8 + c) = w;
                    }
                } else {
                    int cc = colb - 512, h = cc >> 3, c = cc & 7;
                    if (ok) {
                        #pragma unroll
                        for (int r = 0; r < 4; ++r)
                            Vh[((size_t)(b_ * 64 + h) * 16 + c + r) * KROWS + vcol] = f2bf(vv[r]);
                    }
                }
            }
        }
    }
}

// ---------------------------------------------------------------- out-projection
// C^T: A=Wo_t [512,512], Bt=AO [2048,512] -> out[(b*512+c)*1024+n] + bias + residual
// grid (16, 8): 128 blocks (64-row tiles over channels)
__global__ __launch_bounds__(256) void gemm_out(
        const unsigned short* __restrict__ Wo_t, const unsigned short* __restrict__ AO,
        const float* __restrict__ bias, const float* __restrict__ resid,
        float* __restrict__ out) {
    __shared__ alignas(16) unsigned short AsS[2 * 64 * 32];
    __shared__ alignas(16) unsigned short BsS[2 * 128 * 32];
    floatx4 acc[2][4] = {};
    int tid = threadIdx.x;
    int wv = tid >> 6, ln = tid & 63;
    int quad = ln >> 4, l16 = ln & 15;
    int wr = wv >> 1, wc = wv & 1;
    int n0 = blockIdx.x * 128, m0 = blockIdx.y * 64;
    gemm_core64<false>(Wo_t, 512, AO, 512, m0, n0, AsS, BsS, acc);
    #pragma unroll
    for (int i = 0; i < 2; ++i) {
        int cbase = m0 + wr * 32 + i * 16 + quad * 4;
        #pragma unroll
        for (int j = 0; j < 4; ++j) {
            int ng = n0 + wc * 64 + j * 16 + l16;
            int b = ng >> 10, n = ng & 1023;
            float4 res = *(const float4*)(resid + ((size_t)(b * 1024 + n)) * 512 + cbase);
            float rr[4] = {res.x, res.y, res.z, res.w};
            #pragma unroll
            for (int r = 0; r < 4; ++r) {
                int c = cbase + r;
                out[((size_t)(b * 512 + c)) * 1024 + n] = acc[i][j][r] + bias[c] + rr[r];
            }
        }
    }
}

// ---------------------------------------------------------------- MFMA flash attention
// Zero LDS / zero barriers in the main loop (V kv-permuted so S-output = PV A-frag).
__global__ __launch_bounds__(256) void attn_mfma(
        const unsigned short* __restrict__ Qh,   // [2][64][1024][8]
        const unsigned short* __restrict__ Kh,   // [2][64][KROWS][8]
        const unsigned short* __restrict__ Vh,   // [2][64][16][KROWS] (kv-permuted)
        unsigned short* __restrict__ AO) {       // [2048][512]
    int x = blockIdx.x;
    int h = x & 63, qt = (x >> 6) & 7, b = x >> 9;
    int tid = threadIdx.x, wv = tid >> 6, ln = tid & 63;
    int quad = ln >> 4, l16 = ln & 15;
    int q0r = qt * 128 + wv * 32;
    int bh = b * 64 + h;

    short8 qa = {}, qb = {};
    if (quad == 0) {
        qa = *(const short8*)(Qh + ((size_t)bh * 1024 + q0r + l16) * 8);
        qb = *(const short8*)(Qh + ((size_t)bh * 1024 + q0r + 16 + l16) * 8);
    }
    const unsigned short* Kb = Kh + (size_t)bh * KROWS * 8;
    const unsigned short* Vb = Vh + ((size_t)bh * 16 + l16) * KROWS;

    floatx4 acca = {}, accb = {};

    for (int base = 0; base < 1088; base += 32) {
        short8 k0 = *(const short8*)(Kb + (size_t)(base + l16) * 8);
        short8 k1 = *(const short8*)(Kb + (size_t)(base + 16 + l16) * 8);
        short8 vf = *(const short8*)(Vb + base + quad * 8);
        floatx4 z = {};
        floatx4 s0a = __builtin_amdgcn_mfma_f32_16x16x32_bf16(k0, qa, z, 0, 0, 0);
        floatx4 s1a = __builtin_amdgcn_mfma_f32_16x16x32_bf16(k1, qa, z, 0, 0, 0);
        floatx4 s0b = __builtin_amdgcn_mfma_f32_16x16x32_bf16(k0, qb, z, 0, 0, 0);
        floatx4 s1b = __builtin_amdgcn_mfma_f32_16x16x32_bf16(k1, qb, z, 0, 0, 0);
        union { ushortx4 hlf[2]; short8 s; } ua, ub;
        #pragma unroll
        for (int r = 0; r < 4; ++r) {
            ua.hlf[0][r] = rtzbf(__builtin_amdgcn_exp2f(s0a[r]));
            ua.hlf[1][r] = rtzbf(__builtin_amdgcn_exp2f(s1a[r]));
            ub.hlf[0][r] = rtzbf(__builtin_amdgcn_exp2f(s0b[r]));
            ub.hlf[1][r] = rtzbf(__builtin_amdgcn_exp2f(s1b[r]));
        }
        acca = __builtin_amdgcn_mfma_f32_16x16x32_bf16(ua.s, vf, acca, 0, 0, 0);
        accb = __builtin_amdgcn_mfma_f32_16x16x32_bf16(ub.s, vf, accb, 0, 0, 0);
    }
    {   // tail chunk base=1088: valid kvrel 0..12 (13 of 32)
        short8 k0 = *(const short8*)(Kb + (size_t)(1088 + l16) * 8);
        short8 vf = *(const short8*)(Vb + 1088 + quad * 8);
        floatx4 z = {};
        floatx4 s0a = __builtin_amdgcn_mfma_f32_16x16x32_bf16(k0, qa, z, 0, 0, 0);
        floatx4 s0b = __builtin_amdgcn_mfma_f32_16x16x32_bf16(k0, qb, z, 0, 0, 0);
        union { ushortx4 hlf[2]; short8 s; } ua, ub;
        #pragma unroll
        for (int r = 0; r < 4; ++r) {
            bool valid = (quad * 4 + r) < 13;
            ua.hlf[0][r] = valid ? rtzbf(__builtin_amdgcn_exp2f(s0a[r])) : (unsigned short)0;
            ua.hlf[1][r] = 0;
            ub.hlf[0][r] = valid ? rtzbf(__builtin_amdgcn_exp2f(s0b[r])) : (unsigned short)0;
            ub.hlf[1][r] = 0;
        }
        acca = __builtin_amdgcn_mfma_f32_16x16x32_bf16(ua.s, vf, acca, 0, 0, 0);
        accb = __builtin_amdgcn_mfma_f32_16x16x32_bf16(ub.s, vf, accb, 0, 0, 0);
    }

    #pragma unroll
    for (int r = 0; r < 4; ++r) {
        float la = __shfl(acca[r], (ln & 48) + 8, 64);    // l from ones-column (ch=8)
        float lb = __shfl(accb[r], (ln & 48) + 8, 64);
        if (l16 < 8) {
            AO[((size_t)(b * 1024 + q0r + quad * 4 + r)) * 512 + h * 8 + l16] =
                f2bf(acca[r] / la);
            AO[((size_t)(b * 1024 + q0r + 16 + quad * 4 + r)) * 512 + h * 8 + l16] =
                f2bf(accb[r] / lb);
        }
    }
}

// ---------------------------------------------------------------- launcher
extern "C" void kernel_launch(void* const* d_in, const int* in_sizes, int n_in,
                              void* d_out, int out_size, void* d_ws, size_t ws_size,
                              hipStream_t stream) {
    const float* x    = (const float*)d_in[0];
    const float* enc  = (const float*)d_in[1];
    const float* gn_s = (const float*)d_in[2];
    const float* gn_b = (const float*)d_in[3];
    const float* ln_s = (const float*)d_in[4];
    const float* ln_b = (const float*)d_in[5];
    const float* Wq  = (const float*)d_in[6];   const float* bq  = (const float*)d_in[7];
    const float* Wk  = (const float*)d_in[8];   const float* bk  = (const float*)d_in[9];
    const float* Wv  = (const float*)d_in[10];  const float* bv  = (const float*)d_in[11];
    const float* Wak = (const float*)d_in[12];  const float* bak = (const float*)d_in[13];
    const float* Wav = (const float*)d_in[14];  const float* bav = (const float*)d_in[15];
    const float* Wo  = (const float*)d_in[16];  const float* bo  = (const float*)d_in[17];
    float* out = (float*)d_out;

    char* p = (char*)d_ws;
    auto alloc = [&](size_t bytes) { char* r = p; p += (bytes + 255) & ~255ULL; return r; };
    unsigned short* hs_bf  = (unsigned short*)alloc((size_t)2048 * 512 * 2);
    unsigned short* enc_bf = (unsigned short*)alloc((size_t)154 * 768 * 2);
    unsigned short* Wqkv_t = (unsigned short*)alloc((size_t)1536 * 512 * 2);
    unsigned short* Wakv_t = (unsigned short*)alloc((size_t)1024 * 768 * 2);
    unsigned short* Wo_t   = (unsigned short*)alloc((size_t)512 * 512 * 2);
    float* bqkv = (float*)alloc(1536 * 4);
    float* bakv = (float*)alloc(1024 * 4);
    unsigned short* Qh = (unsigned short*)alloc((size_t)2 * 64 * 1024 * 8 * 2);
    unsigned short* Kh = (unsigned short*)alloc((size_t)2 * 64 * KROWS * 8 * 2);
    unsigned short* Vh = (unsigned short*)alloc((size_t)2 * 64 * 16 * KROWS * 2);
    unsigned short* AO = (unsigned short*)alloc((size_t)2048 * 512 * 2);

    prep_all<<<2580, 256, 0, stream>>>(
        Wq, Wk, Wv, Wak, Wav, Wo, bq, bk, bv, bak, bav,
        enc, ln_s, ln_b, x, gn_s, gn_b,
        Wqkv_t, Wakv_t, Wo_t, bqkv, bakv, enc_bf, hs_bf, Vh);

    proj_gemm<<<408, 256, 0, stream>>>(
        hs_bf, enc_bf, Wqkv_t, Wakv_t, bqkv, bakv, Qh, Kh, Vh);

    attn_mfma<<<BSZ * NHEAD * 8, 256, 0, stream>>>(Qh, Kh, Vh, AO);

    gemm_out<<<dim3(16, 8), 256, 0, stream>>>(Wo_t, AO, bo, x, out);

    (void)in_sizes; (void)n_in; (void)out_size; (void)ws_size;
}